// Round 11
// baseline (166.551 us; speedup 1.0000x reference)
//
#include <hip/hip_runtime.h>
#include <hip/hip_bf16.h>
#include <cstdint>

#define T_SEQ 2048
#define DIM   1024
#define NHEAD 16
#define NKVH  8
#define HDIM  64
#define QKVN  3584   // 2048 (q) + 1024 (k) + 512 (v)

static constexpr float LAMBDA_INIT_F = 0.3555090675909693f;
static constexpr float ONE_MINUS_LI  = 0.6444909324090307f;
static constexpr float QSCALE_EXP2   = 0.1803368801111144f;  // 0.125 * log2(e)

typedef __bf16 bf16x8 __attribute__((ext_vector_type(8)));
typedef float  f32x4  __attribute__((ext_vector_type(4)));

static __device__ __forceinline__ ushort f2bf(float f) {
  union { float f; uint32_t u; } x; x.f = f;
  uint32_t u = x.u;
  uint32_t r = (u + 0x7fffu + ((u >> 16) & 1u)) >> 16;
  return (ushort)r;
}
static __device__ __forceinline__ float bf2f(ushort u) {
  union { uint32_t u; float f; } x; x.u = ((uint32_t)u) << 16; return x.f;
}
static __device__ __forceinline__ f32x4 zero4() {
  f32x4 z = {0.f, 0.f, 0.f, 0.f}; return z;
}
// Fragment-interleaved layout: within each 32-element k-block, quad q (=k>>2) is
// stored at offset ((q&3)<<3) + ((q>>2)<<2). A lane's 8 frag elements
// {4g..4g+3, 16+4g..19+4g} land contiguously at [8g..8g+7] -> one 16B load.
static __device__ __forceinline__ bf16x8 ldfrag128(const ushort* p) {
  union { bf16x8 v; uint4 u; } r;
  r.u = *(const uint4*)p;
  return r.v;
}
// async global->LDS, 16B per lane; lds dest = base + lane*16 (wave-uniform base)
static __device__ __forceinline__ void gll16(const ushort* g, ushort* l) {
  __builtin_amdgcn_global_load_lds(
      (const __attribute__((address_space(1))) uint32_t*)g,
      (__attribute__((address_space(3))) uint32_t*)l, 16, 0, 0);
}

// ---------------- fused fp32->bf16 conversion, frag-interleaved output -------------
__global__ void cvt_all(const float* __restrict__ x,  const float* __restrict__ wq,
                        const float* __restrict__ wk, const float* __restrict__ wv,
                        const float* __restrict__ wo,
                        ushort* __restrict__ xb, ushort* __restrict__ Wb,
                        ushort* __restrict__ Wob) {
  int g = (blockIdx.x * 256 + threadIdx.x) * 4;   // < 6815744, 4-aligned
  float4 v; ushort* dst; int j;
  if (g < 2097152) {
    v = *(const float4*)(x + g); dst = xb; j = g;
  } else if (g < 5767168) {
    j = g - 2097152;
    const float* src = (j < 2097152) ? (wq + j)
                     : (j < 3145728) ? (wk + (j - 2097152))
                                     : (wv + (j - 3145728));
    v = *(const float4*)src; dst = Wb;
  } else {
    j = g - 5767168;
    v = *(const float4*)(wo + j); dst = Wob;
  }
  int q = (j & 31) >> 2;                         // quad within 32-block
  int jp = (j & ~31) + ((q & 3) << 3) + ((q >> 2) << 2);
  ushort4 o4;
  o4.x = f2bf(v.x); o4.y = f2bf(v.y); o4.z = f2bf(v.z); o4.w = f2bf(v.w);
  *(ushort4*)(dst + jp) = o4;
}

__global__ void lam_kernel(const float* __restrict__ lq1, const float* __restrict__ lk1,
                           const float* __restrict__ lq2, const float* __restrict__ lk2,
                           float* __restrict__ lam) {
  int lane = threadIdx.x;  // 64 threads
  float p1 = lq1[lane] * lk1[lane];
  float p2 = lq2[lane] * lk2[lane];
  #pragma unroll
  for (int off = 32; off >= 1; off >>= 1) {
    p1 += __shfl_down(p1, off);
    p2 += __shfl_down(p2, off);
  }
  if (lane == 0) *lam = expf(p1) - expf(p2) + LAMBDA_INIT_F;
}

// ---------------- GEMM (m97 + T1 swizzle), frag-interleaved inputs, b128 reads -----
template<int BF16OUT>
__global__ __launch_bounds__(256) void gemm_bt(const ushort* __restrict__ A,
                                               const ushort* __restrict__ W,
                                               void* __restrict__ Cout,
                                               int M, int N, int K) {
  __shared__ __align__(16) ushort As[128 * 32];
  __shared__ __align__(16) ushort Ws[128 * 32];
  const int tid  = threadIdx.x;
  const int lane = tid & 63;
  const int w    = tid >> 6;
  const int wr   = w >> 1, wc = w & 1;
  const int nwg = gridDim.x * gridDim.y;
  int id  = blockIdx.x * gridDim.y + blockIdx.y;
  int sw  = (id & 7) * (nwg >> 3) + (id >> 3);
  const int bm = (sw % gridDim.y) * 128;
  const int bn = (sw / gridDim.y) * 128;
  const int fr = lane & 15;
  const int fg = (lane >> 4) * 4;
  const int g8 = (lane >> 4) * 8;

  f32x4 acc[4][4];
  #pragma unroll
  for (int m = 0; m < 4; ++m)
    #pragma unroll
    for (int n = 0; n < 4; ++n) acc[m][n] = zero4();

  const int col  = (lane & 3) * 8;
  const int row0 = w * 16 + (lane >> 2);
  const int row1 = row0 + 64;
  const ushort* ga0 = A + (size_t)(bm + row0) * K + col;
  const ushort* ga1 = A + (size_t)(bm + row1) * K + col;
  const ushort* gw0 = W + (size_t)(bn + row0) * K + col;
  const ushort* gw1 = W + (size_t)(bn + row1) * K + col;
  ushort* la0 = As + (w * 512);
  ushort* la1 = As + (w * 512) + 2048;
  ushort* lw0 = Ws + (w * 512);
  ushort* lw1 = Ws + (w * 512) + 2048;

  for (int k0 = 0; k0 < K; k0 += 32) {
    gll16(ga0 + k0, la0);
    gll16(ga1 + k0, la1);
    gll16(gw0 + k0, lw0);
    gll16(gw1 + k0, lw1);
    __syncthreads();
    bf16x8 af[4], bfr[4];
    #pragma unroll
    for (int m = 0; m < 4; ++m) af[m]  = ldfrag128(&As[(wr*64 + m*16 + fr) * 32 + g8]);
    #pragma unroll
    for (int n = 0; n < 4; ++n) bfr[n] = ldfrag128(&Ws[(wc*64 + n*16 + fr) * 32 + g8]);
    #pragma unroll
    for (int m = 0; m < 4; ++m)
      #pragma unroll
      for (int n = 0; n < 4; ++n)
        acc[m][n] = __builtin_amdgcn_mfma_f32_16x16x32_bf16(af[m], bfr[n], acc[m][n], 0, 0, 0);
    __syncthreads();
  }

  #pragma unroll
  for (int m = 0; m < 4; ++m)
    #pragma unroll
    for (int n = 0; n < 4; ++n)
      #pragma unroll
      for (int i = 0; i < 4; ++i) {
        int row = bm + wr*64 + m*16 + fg + i;
        int colg = bn + wc*64 + n*16 + fr;
        float v = acc[m][n][i];
        if (BF16OUT) ((ushort*)Cout)[(size_t)row * N + colg] = f2bf(v);
        else         ((float*)Cout)[(size_t)row * N + colg]  = v;
      }
}

// ---------------- fused RoPE Q, RoPE K, pack V -> frag-interleaved layouts ---------
// Q scaled by 0.125*log2(e). Qr/Kr: d-dim permuted per 32-block; Vt: t-dim permuted.
__global__ void reorg(const ushort* __restrict__ QKV, ushort* __restrict__ Qr,
                      ushort* __restrict__ Kr, ushort* __restrict__ Vt,
                      const float* __restrict__ fc, const float* __restrict__ fs) {
  int idx = blockIdx.x * 256 + threadIdx.x;   // < 917504
  if (idx < 786432) {
    // RoPE, 4 interleaved pairs = 8 consecutive logical d per thread
    int nheads, col_off; ushort* dst; float scale; int id;
    if (idx < 524288) { id = idx * 4; nheads = NHEAD; col_off = 0; dst = Qr; scale = QSCALE_EXP2; }
    else { id = (idx - 524288) * 4; nheads = NKVH; col_off = 2048; dst = Kr; scale = 1.0f; }
    int per_t = nheads * 64;
    int t  = id / per_t;
    int r  = id - t * per_t;
    int hh = r >> 6;
    int c2 = (r >> 5) & 1;
    int j  = r & 31;                      // multiple of 4; logical d0 = 2j
    int cl = col_off + hh * 128 + c2 * 64 + 2 * j;
    uint4 raw = *(const uint4*)(QKV + (size_t)t * QKVN + cl);
    const ushort* rp = (const ushort*)&raw;
    float c4[4], s4[4];
    *(float4*)c4 = *(const float4*)(fc + t * 32 + j);
    *(float4*)s4 = *(const float4*)(fs + t * 32 + j);
    ushort outv[8];
    #pragma unroll
    for (int p = 0; p < 4; ++p) {
      float rv = bf2f(rp[2*p]), iv = bf2f(rp[2*p + 1]);
      outv[2*p]     = f2bf((rv * c4[p] - iv * s4[p]) * scale);
      outv[2*p + 1] = f2bf((rv * s4[p] + iv * c4[p]) * scale);
    }
    int d0 = 2 * j;
    int o  = d0 & 31;                     // 0,8,16,24
    int q0 = o >> 2;                      // 0,2,4,6
    int s0 = ((q0 & 3) << 3) + ((q0 >> 2) << 2);
    int s1 = (((q0+1) & 3) << 3) + (((q0+1) >> 2) << 2);
    size_t ob = ((size_t)(c2 * nheads + hh) * T_SEQ + t) * HDIM + (d0 & ~31);
    *(uint2*)(dst + ob + s0) = *(const uint2*)(outv);
    *(uint2*)(dst + ob + s1) = *(const uint2*)(outv + 4);
  } else {
    // V transpose: 8 t-consecutive elems, t-permuted within 32-blocks
    int id = (idx - 786432) * 8;           // < 1048576
    int t = id & (T_SEQ - 1);              // multiple of 8
    int rest = id >> 11;                   // kh*64 + d
    ushort outv[8];
    #pragma unroll
    for (int p = 0; p < 8; ++p) outv[p] = QKV[(size_t)(t + p) * QKVN + 3072 + rest];
    int o  = t & 31;
    int q0 = o >> 2;
    int s0 = ((q0 & 3) << 3) + ((q0 >> 2) << 2);
    int s1 = (((q0+1) & 3) << 3) + (((q0+1) >> 2) << 2);
    size_t ob = (size_t)rest * T_SEQ + (t & ~31);
    *(uint2*)(Vt + ob + s0) = *(const uint2*)(outv);
    *(uint2*)(Vt + ob + s1) = *(const uint2*)(outv + 4);
  }
}

// ---------------- flash attention: no in-loop LDS, K reg-double-buffered -----------
// 512 blocks = (head, qb). Wave w: stream st = w>>1, q-half qh = w&1 (32 q-rows).
// K/V fragments direct from L2 (frag-interleaved global). K is double-buffered in
// registers (kfA/kfB, 2-unrolled loop) so QK never waits on L2; V self-hides.
// Softmax row-reductions are depth-4 trees. Epilogue unchanged.
__global__ __launch_bounds__(256) void attn_kernel(const ushort* __restrict__ Qr,
                                                   const ushort* __restrict__ Kr,
                                                   const ushort* __restrict__ Vt,
                                                   const float* __restrict__ lamp,
                                                   float* __restrict__ Yf,
                                                   float* __restrict__ part) {
  const int bx = blockIdx.x;          // 0..511
  const int h  = bx & 15;
  const int jb = bx >> 4;             // pair (jb, jb+16) sums to 32 tiles
  const int qb = (jb < 16) ? (31 - jb) : (jb - 16);
  const int kh = h >> 1;
  const int tid = threadIdx.x;
  const int lane = tid & 63;
  const int w   = tid >> 6;
  const int st  = w >> 1;             // stream 0/1
  const int qh  = w & 1;              // q-half 0/1
  const int fr  = lane & 15;
  const int fg  = (lane >> 4) * 4;
  const int g8  = (lane >> 4) * 8;

  __shared__ float ob[64 * 64];       // epilogue O2 exchange (16 KB)
  __shared__ float sb[8];

  // Q fragments for this wave's stream, two 16-q chunks (frag-interleaved global)
  bf16x8 qf[2][2];                     // [qs][ks]
  #pragma unroll
  for (int qs = 0; qs < 2; ++qs) {
    const int row = qb * 64 + qh * 32 + qs * 16 + fr;
    const ushort* qp = Qr + ((size_t)(st * NHEAD + h) * T_SEQ + row) * HDIM;
    qf[qs][0] = ldfrag128(qp + g8);
    qf[qs][1] = ldfrag128(qp + 32 + g8);
  }

  float m_[2] = {-__builtin_inff(), -__builtin_inff()};
  float l_[2] = {0.f, 0.f};
  f32x4 o_[2][4];
  #pragma unroll
  for (int qs = 0; qs < 2; ++qs)
    #pragma unroll
    for (int dn = 0; dn < 4; ++dn) o_[qs][dn] = zero4();

  // per-lane fragment base pointers (row picked by fr, 16B chunk by g8)
  const ushort* Kbase = Kr + ((size_t)(st * NKVH + kh) * T_SEQ + fr) * HDIM + g8;
  const ushort* Vbase = Vt + ((size_t)(kh * 64 + fr) * T_SEQ) + g8;

  bf16x8 kfA[4][2], kfB[4][2], vf[4][2];

#define LOADK(KF, KT) { \
    const ushort* kp_ = Kbase + (size_t)((KT) * 64) * HDIM; \
    _Pragma("unroll") \
    for (int n_ = 0; n_ < 4; ++n_) { \
      KF[n_][0] = ldfrag128(kp_); \
      KF[n_][1] = ldfrag128(kp_ + 32); \
      kp_ += 16 * HDIM; \
    } }

#define LOADV(KT) { \
    const ushort* vp_ = Vbase + (KT) * 64; \
    _Pragma("unroll") \
    for (int dn_ = 0; dn_ < 4; ++dn_) { \
      vf[dn_][0] = ldfrag128(vp_); \
      vf[dn_][1] = ldfrag128(vp_ + 32); \
      vp_ += (size_t)16 * T_SEQ; \
    } }

  auto compute_tile = [&](bf16x8 (&kf)[4][2], int ktv) {
    // S^T: mfma(K rows, Q cols); one K frag serves both q-chunks
    float sv[2][4][4];
    #pragma unroll
    for (int n = 0; n < 4; ++n) {
      f32x4 a0 = zero4(), a1 = zero4();
      #pragma unroll
      for (int ks = 0; ks < 2; ++ks) {
        a0 = __builtin_amdgcn_mfma_f32_16x16x32_bf16(kf[n][ks], qf[0][ks], a0, 0, 0, 0);
        a1 = __builtin_amdgcn_mfma_f32_16x16x32_bf16(kf[n][ks], qf[1][ks], a1, 0, 0, 0);
      }
      #pragma unroll
      for (int i = 0; i < 4; ++i) { sv[0][n][i] = a0[i]; sv[1][n][i] = a1[i]; }
    }
    if (ktv == qb) {                 // causal mask on diagonal tile
      #pragma unroll
      for (int qs = 0; qs < 2; ++qs) {
        const int qloc = qh*32 + qs*16 + fr;
        #pragma unroll
        for (int n = 0; n < 4; ++n)
          #pragma unroll
          for (int i = 0; i < 4; ++i)
            if (n*16 + fg + i > qloc) sv[qs][n][i] = -__builtin_inff();
      }
    }

    bf16x8 pa[2][2];
    #pragma unroll
    for (int qs = 0; qs < 2; ++qs) {
      // depth-4 pairwise max tree over the 16 in-lane values
      float r8[8];
      #pragma unroll
      for (int z = 0; z < 8; ++z)
        r8[z] = fmaxf(sv[qs][z>>1][(z&1)*2], sv[qs][z>>1][(z&1)*2 + 1]);
      float r4a = fmaxf(r8[0], r8[1]), r4b = fmaxf(r8[2], r8[3]);
      float r4c = fmaxf(r8[4], r8[5]), r4d = fmaxf(r8[6], r8[7]);
      float rm = fmaxf(fmaxf(r4a, r4b), fmaxf(r4c, r4d));
      rm = fmaxf(rm, __shfl_xor(rm, 16));
      rm = fmaxf(rm, __shfl_xor(rm, 32));
      if (!__all(rm <= m_[qs] + 8.f)) {   // defer-max (exp2 domain, THR=8)
        float mnew = fmaxf(m_[qs], rm);
        float sc = __builtin_amdgcn_exp2f(m_[qs] - mnew);
        m_[qs] = mnew;
        l_[qs] *= sc;
        float scs[4];
        #pragma unroll
        for (int i = 0; i < 4; ++i) scs[i] = __shfl(sc, fg + i);
        #pragma unroll
        for (int dn = 0; dn < 4; ++dn)
          #pragma unroll
          for (int i = 0; i < 4; ++i) o_[qs][dn][i] *= scs[i];
      }
      #pragma unroll
      for (int n = 0; n < 4; ++n)
        #pragma unroll
        for (int i = 0; i < 4; ++i)
          sv[qs][n][i] = __builtin_amdgcn_exp2f(sv[qs][n][i] - m_[qs]);
      // depth-4 pairwise sum tree
      float s8[8];
      #pragma unroll
      for (int z = 0; z < 8; ++z)
        s8[z] = sv[qs][z>>1][(z&1)*2] + sv[qs][z>>1][(z&1)*2 + 1];
      float s4a = s8[0] + s8[1], s4b = s8[2] + s8[3];
      float s4c = s8[4] + s8[5], s4d = s8[6] + s8[7];
      float rs = (s4a + s4b) + (s4c + s4d);
      rs += __shfl_xor(rs, 16);
      rs += __shfl_xor(rs, 32);
      l_[qs] += rs;
      #pragma unroll
      for (int ks = 0; ks < 2; ++ks)
        #pragma unroll
        for (int n2 = 0; n2 < 2; ++n2)
          #pragma unroll
          for (int i = 0; i < 4; ++i)
            pa[qs][ks][n2*4 + i] = (__bf16)sv[qs][2*ks + n2][i];
    }

    // O += P @ V; one V frag serves both q-chunks
    #pragma unroll
    for (int ks = 0; ks < 2; ++ks)
      #pragma unroll
      for (int dn = 0; dn < 4; ++dn) {
        o_[0][dn] = __builtin_amdgcn_mfma_f32_16x16x32_bf16(pa[0][ks], vf[dn][ks], o_[0][dn], 0, 0, 0);
        o_[1][dn] = __builtin_amdgcn_mfma_f32_16x16x32_bf16(pa[1][ks], vf[dn][ks], o_[1][dn], 0, 0, 0);
      }
  };

  // software-pipelined main loop: K double-buffered, V self-hiding
  LOADK(kfA, 0);
  int kt = 0;
  for (; kt + 1 <= qb; kt += 2) {
    LOADV(kt);
    LOADK(kfB, kt + 1);
    compute_tile(kfA, kt);
    LOADV(kt + 1);
    if (kt + 2 <= qb) LOADK(kfA, kt + 2);
    compute_tile(kfB, kt + 1);
  }
  if (kt == qb) {
    LOADV(kt);
    compute_tile(kfA, kt);
  }
#undef LOADK
#undef LOADV

  // epilogue: normalize; exchange stream-1 O via LDS; combine + Yf + LN partials
  float iq[2][4];
  #pragma unroll
  for (int qs = 0; qs < 2; ++qs) {
    float inv = __builtin_amdgcn_rcpf(l_[qs]);
    #pragma unroll
    for (int i = 0; i < 4; ++i) iq[qs][i] = __shfl(inv, fg + i);
  }
  __syncthreads();
  if (st == 1) {
    #pragma unroll
    for (int qs = 0; qs < 2; ++qs)
      #pragma unroll
      for (int dn = 0; dn < 4; ++dn)
        #pragma unroll
        for (int i = 0; i < 4; ++i)
          ob[(qh*32 + qs*16 + fg + i)*64 + dn*16 + fr] = o_[qs][dn][i] * iq[qs][i];
  }
  __syncthreads();
  if (st == 0) {
    const float lam = *lamp;
    float s = 0.f, s2 = 0.f;
    #pragma unroll
    for (int qs = 0; qs < 2; ++qs)
      #pragma unroll
      for (int dn = 0; dn < 4; ++dn)
        #pragma unroll
        for (int i = 0; i < 4; ++i) {
          int r64 = qh*32 + qs*16 + fg + i;
          int d   = dn*16 + fr;
          float v = o_[qs][dn][i] * iq[qs][i] - lam * ob[r64*64 + d];
          Yf[(size_t)(qb*64 + r64) * DIM + h*64 + d] = v;
          s += v; s2 += v * v;
        }
    #pragma unroll
    for (int off = 1; off <= 32; off <<= 1) {
      s  += __shfl_xor(s, off);
      s2 += __shfl_xor(s2, off);
    }
    if (lane == 0) { sb[w] = s; sb[4 + w] = s2; }   // w in {0,1}
  }
  __syncthreads();
  if (tid == 0) {
    part[bx]       = sb[0] + sb[1];
    part[512 + bx] = sb[4] + sb[5];
  }
}

// ---------------- finalize per-head stats ----------------
__global__ void stats_final(const float* __restrict__ part, float* __restrict__ stat) {
  int hh = threadIdx.x;
  if (hh < 16) {
    float S = 0.f, S2 = 0.f;
    #pragma unroll
    for (int j = 0; j < 32; ++j) { S += part[j*16 + hh]; S2 += part[512 + j*16 + hh]; }
    const float N = (float)(T_SEQ * HDIM);
    float mean = S / N;
    float var  = S2 / N - mean * mean;
    stat[hh]      = mean;
    stat[16 + hh] = rsqrtf(var + 1e-5f);
  }
}

// Yb written frag-interleaved (gemm2 expects it)
__global__ void norm_cvt(const float* __restrict__ Y, const float* __restrict__ stats,
                         ushort* __restrict__ Yb) {
  int idx = (blockIdx.x * 256 + threadIdx.x) * 4;   // < T*DIM, 4-aligned
  int col = idx & (DIM - 1);
  int h = col >> 6;
  float mean = stats[h], isd = stats[16 + h] * ONE_MINUS_LI;
  float4 v = *(const float4*)(Y + idx);
  ushort4 o4;
  o4.x = f2bf((v.x - mean) * isd);
  o4.y = f2bf((v.y - mean) * isd);
  o4.z = f2bf((v.z - mean) * isd);
  o4.w = f2bf((v.w - mean) * isd);
  int q = (col & 31) >> 2;
  int idxp = (idx & ~31) + ((q & 3) << 3) + ((q >> 2) << 2);
  *(ushort4*)(Yb + idxp) = o4;
}

// ---------------- launch ----------------
extern "C" void kernel_launch(void* const* d_in, const int* in_sizes, int n_in,
                              void* d_out, int out_size, void* d_ws, size_t ws_size,
                              hipStream_t stream) {
  const float* x   = (const float*)d_in[0];
  const float* fc  = (const float*)d_in[1];
  const float* fs  = (const float*)d_in[2];
  const float* wq  = (const float*)d_in[3];
  const float* wk  = (const float*)d_in[4];
  const float* wv  = (const float*)d_in[5];
  const float* wo  = (const float*)d_in[6];
  const float* lq1 = (const float*)d_in[7];
  const float* lk1 = (const float*)d_in[8];
  const float* lq2 = (const float*)d_in[9];
  const float* lk2 = (const float*)d_in[10];
  float* out = (float*)d_out;

  char* ws = (char*)d_ws;
  const size_t OFF_WOB  = 0;                 // 2 MB, live till end
  const size_t OFF_XB   = 2097152;           // 4 MB, dead after gemm1
  const size_t OFF_WB   = 6291456;           // 7 MB, dead after gemm1
  const size_t OFF_QKV  = 13631488;          // 14.68 MB, dead after reorg
  const size_t OFF_QR   = 28311552;          // 8 MB
  const size_t OFF_KR   = 36700160;          // 4 MB
  const size_t OFF_VT   = 40894464;          // 2 MB
  const size_t OFF_Y    = 18874368;          // 8 MB over dead QKV tail
  const size_t OFF_YB   = 42991616;          // 4 MB
  const size_t OFF_ST   = 47185920;          // stats + lam + partials

  ushort* xb   = (ushort*)(ws + OFF_XB);
  ushort* Wb   = (ushort*)(ws + OFF_WB);
  ushort* Wob  = (ushort*)(ws + OFF_WOB);
  ushort* QKVb = (ushort*)(ws + OFF_QKV);
  ushort* Qr   = (ushort*)(ws + OFF_QR);
  ushort* Kr   = (ushort*)(ws + OFF_KR);
  ushort* Vt   = (ushort*)(ws + OFF_VT);
  float*  Yf   = (float*)(ws + OFF_Y);
  ushort* Yb   = (ushort*)(ws + OFF_YB);
  float*  stat = (float*)(ws + OFF_ST);
  float*  lamp = stat + 32;
  float*  part = stat + 64;                  // 1024 floats

  cvt_all<<<6656, 256, 0, stream>>>(x, wq, wk, wv, wo, xb, Wb, Wob);
  lam_kernel<<<1, 64, 0, stream>>>(lq1, lk1, lq2, lk2, lamp);

  gemm_bt<1><<<dim3(QKVN/128, T_SEQ/128), 256, 0, stream>>>(xb, Wb, QKVb, T_SEQ, QKVN, DIM);

  reorg<<<3584, 256, 0, stream>>>(QKVb, Qr, Kr, Vt, fc, fs);

  attn_kernel<<<512, 256, 0, stream>>>(Qr, Kr, Vt, lamp, Yf, part);

  stats_final<<<1, 64, 0, stream>>>(part, stat);
  norm_cvt<<<2048, 256, 0, stream>>>(Yf, stat, Yb);

  gemm_bt<0><<<dim3(DIM/128, T_SEQ/128), 256, 0, stream>>>(Yb, Wob, out, T_SEQ, DIM, DIM);
}

// Round 12
// 147.133 us; speedup vs baseline: 1.1320x; 1.1320x over previous
//
#include <hip/hip_runtime.h>
#include <hip/hip_bf16.h>
#include <cstdint>

#define T_SEQ 2048
#define DIM   1024
#define NHEAD 16
#define NKVH  8
#define HDIM  64
#define QKVN  3584   // 2048 (q) + 1024 (k) + 512 (v)

static constexpr float LAMBDA_INIT_F = 0.3555090675909693f;
static constexpr float ONE_MINUS_LI  = 0.6444909324090307f;
static constexpr float QSCALE_EXP2   = 0.1803368801111144f;  // 0.125 * log2(e)

typedef __bf16 bf16x8 __attribute__((ext_vector_type(8)));
typedef float  f32x4  __attribute__((ext_vector_type(4)));

static __device__ __forceinline__ ushort f2bf(float f) {
  union { float f; uint32_t u; } x; x.f = f;
  uint32_t u = x.u;
  uint32_t r = (u + 0x7fffu + ((u >> 16) & 1u)) >> 16;
  return (ushort)r;
}
static __device__ __forceinline__ float bf2f(ushort u) {
  union { uint32_t u; float f; } x; x.u = ((uint32_t)u) << 16; return x.f;
}
static __device__ __forceinline__ f32x4 zero4() {
  f32x4 z = {0.f, 0.f, 0.f, 0.f}; return z;
}
// Fragment-interleaved layout: within each 32-element k-block, quad q (=k>>2) is
// stored at offset ((q&3)<<3) + ((q>>2)<<2). A lane's 8 frag elements
// {4g..4g+3, 16+4g..19+4g} land contiguously at [8g..8g+7] -> one 16B load.
static __device__ __forceinline__ bf16x8 ldfrag128(const ushort* p) {
  union { bf16x8 v; uint4 u; } r;
  r.u = *(const uint4*)p;
  return r.v;
}
// async global->LDS, 16B per lane; lds dest = base + lane*16 (wave-uniform base)
static __device__ __forceinline__ void gll16(const ushort* g, ushort* l) {
  __builtin_amdgcn_global_load_lds(
      (const __attribute__((address_space(1))) uint32_t*)g,
      (__attribute__((address_space(3))) uint32_t*)l, 16, 0, 0);
}

// ---------------- fused fp32->bf16 conversion, frag-interleaved output -------------
__global__ void cvt_all(const float* __restrict__ x,  const float* __restrict__ wq,
                        const float* __restrict__ wk, const float* __restrict__ wv,
                        const float* __restrict__ wo,
                        ushort* __restrict__ xb, ushort* __restrict__ Wb,
                        ushort* __restrict__ Wob) {
  int g = (blockIdx.x * 256 + threadIdx.x) * 4;   // < 6815744, 4-aligned
  float4 v; ushort* dst; int j;
  if (g < 2097152) {
    v = *(const float4*)(x + g); dst = xb; j = g;
  } else if (g < 5767168) {
    j = g - 2097152;
    const float* src = (j < 2097152) ? (wq + j)
                     : (j < 3145728) ? (wk + (j - 2097152))
                                     : (wv + (j - 3145728));
    v = *(const float4*)src; dst = Wb;
  } else {
    j = g - 5767168;
    v = *(const float4*)(wo + j); dst = Wob;
  }
  int q = (j & 31) >> 2;                         // quad within 32-block
  int jp = (j & ~31) + ((q & 3) << 3) + ((q >> 2) << 2);
  ushort4 o4;
  o4.x = f2bf(v.x); o4.y = f2bf(v.y); o4.z = f2bf(v.z); o4.w = f2bf(v.w);
  *(ushort4*)(dst + jp) = o4;
}

__global__ void lam_kernel(const float* __restrict__ lq1, const float* __restrict__ lk1,
                           const float* __restrict__ lq2, const float* __restrict__ lk2,
                           float* __restrict__ lam) {
  int lane = threadIdx.x;  // 64 threads
  float p1 = lq1[lane] * lk1[lane];
  float p2 = lq2[lane] * lk2[lane];
  #pragma unroll
  for (int off = 32; off >= 1; off >>= 1) {
    p1 += __shfl_down(p1, off);
    p2 += __shfl_down(p2, off);
  }
  if (lane == 0) *lam = expf(p1) - expf(p2) + LAMBDA_INIT_F;
}

// ---------------- GEMM (m97 + T1 swizzle), frag-interleaved inputs, b128 reads -----
template<int BF16OUT>
__global__ __launch_bounds__(256) void gemm_bt(const ushort* __restrict__ A,
                                               const ushort* __restrict__ W,
                                               void* __restrict__ Cout,
                                               int M, int N, int K) {
  __shared__ __align__(16) ushort As[128 * 32];
  __shared__ __align__(16) ushort Ws[128 * 32];
  const int tid  = threadIdx.x;
  const int lane = tid & 63;
  const int w    = tid >> 6;
  const int wr   = w >> 1, wc = w & 1;
  const int nwg = gridDim.x * gridDim.y;
  int id  = blockIdx.x * gridDim.y + blockIdx.y;
  int sw  = (id & 7) * (nwg >> 3) + (id >> 3);
  const int bm = (sw % gridDim.y) * 128;
  const int bn = (sw / gridDim.y) * 128;
  const int fr = lane & 15;
  const int fg = (lane >> 4) * 4;
  const int g8 = (lane >> 4) * 8;

  f32x4 acc[4][4];
  #pragma unroll
  for (int m = 0; m < 4; ++m)
    #pragma unroll
    for (int n = 0; n < 4; ++n) acc[m][n] = zero4();

  const int col  = (lane & 3) * 8;
  const int row0 = w * 16 + (lane >> 2);
  const int row1 = row0 + 64;
  const ushort* ga0 = A + (size_t)(bm + row0) * K + col;
  const ushort* ga1 = A + (size_t)(bm + row1) * K + col;
  const ushort* gw0 = W + (size_t)(bn + row0) * K + col;
  const ushort* gw1 = W + (size_t)(bn + row1) * K + col;
  ushort* la0 = As + (w * 512);
  ushort* la1 = As + (w * 512) + 2048;
  ushort* lw0 = Ws + (w * 512);
  ushort* lw1 = Ws + (w * 512) + 2048;

  for (int k0 = 0; k0 < K; k0 += 32) {
    gll16(ga0 + k0, la0);
    gll16(ga1 + k0, la1);
    gll16(gw0 + k0, lw0);
    gll16(gw1 + k0, lw1);
    __syncthreads();
    bf16x8 af[4], bfr[4];
    #pragma unroll
    for (int m = 0; m < 4; ++m) af[m]  = ldfrag128(&As[(wr*64 + m*16 + fr) * 32 + g8]);
    #pragma unroll
    for (int n = 0; n < 4; ++n) bfr[n] = ldfrag128(&Ws[(wc*64 + n*16 + fr) * 32 + g8]);
    #pragma unroll
    for (int m = 0; m < 4; ++m)
      #pragma unroll
      for (int n = 0; n < 4; ++n)
        acc[m][n] = __builtin_amdgcn_mfma_f32_16x16x32_bf16(af[m], bfr[n], acc[m][n], 0, 0, 0);
    __syncthreads();
  }

  #pragma unroll
  for (int m = 0; m < 4; ++m)
    #pragma unroll
    for (int n = 0; n < 4; ++n)
      #pragma unroll
      for (int i = 0; i < 4; ++i) {
        int row = bm + wr*64 + m*16 + fg + i;
        int colg = bn + wc*64 + n*16 + fr;
        float v = acc[m][n][i];
        if (BF16OUT) ((ushort*)Cout)[(size_t)row * N + colg] = f2bf(v);
        else         ((float*)Cout)[(size_t)row * N + colg]  = v;
      }
}

// ---------------- fused RoPE Q, RoPE K, pack V -> frag-interleaved layouts ---------
// Q scaled by 0.125*log2(e). Qr/Kr: d-dim permuted per 32-block; Vt: t-dim permuted.
__global__ void reorg(const ushort* __restrict__ QKV, ushort* __restrict__ Qr,
                      ushort* __restrict__ Kr, ushort* __restrict__ Vt,
                      const float* __restrict__ fc, const float* __restrict__ fs) {
  int idx = blockIdx.x * 256 + threadIdx.x;   // < 917504
  if (idx < 786432) {
    // RoPE, 4 interleaved pairs = 8 consecutive logical d per thread
    int nheads, col_off; ushort* dst; float scale; int id;
    if (idx < 524288) { id = idx * 4; nheads = NHEAD; col_off = 0; dst = Qr; scale = QSCALE_EXP2; }
    else { id = (idx - 524288) * 4; nheads = NKVH; col_off = 2048; dst = Kr; scale = 1.0f; }
    int per_t = nheads * 64;
    int t  = id / per_t;
    int r  = id - t * per_t;
    int hh = r >> 6;
    int c2 = (r >> 5) & 1;
    int j  = r & 31;                      // multiple of 4; logical d0 = 2j
    int cl = col_off + hh * 128 + c2 * 64 + 2 * j;
    uint4 raw = *(const uint4*)(QKV + (size_t)t * QKVN + cl);
    const ushort* rp = (const ushort*)&raw;
    float c4[4], s4[4];
    *(float4*)c4 = *(const float4*)(fc + t * 32 + j);
    *(float4*)s4 = *(const float4*)(fs + t * 32 + j);
    ushort outv[8];
    #pragma unroll
    for (int p = 0; p < 4; ++p) {
      float rv = bf2f(rp[2*p]), iv = bf2f(rp[2*p + 1]);
      outv[2*p]     = f2bf((rv * c4[p] - iv * s4[p]) * scale);
      outv[2*p + 1] = f2bf((rv * s4[p] + iv * c4[p]) * scale);
    }
    int d0 = 2 * j;
    int o  = d0 & 31;                     // 0,8,16,24
    int q0 = o >> 2;                      // 0,2,4,6
    int s0 = ((q0 & 3) << 3) + ((q0 >> 2) << 2);
    int s1 = (((q0+1) & 3) << 3) + (((q0+1) >> 2) << 2);
    size_t ob = ((size_t)(c2 * nheads + hh) * T_SEQ + t) * HDIM + (d0 & ~31);
    *(uint2*)(dst + ob + s0) = *(const uint2*)(outv);
    *(uint2*)(dst + ob + s1) = *(const uint2*)(outv + 4);
  } else {
    // V transpose: 8 t-consecutive elems, t-permuted within 32-blocks
    int id = (idx - 786432) * 8;           // < 1048576
    int t = id & (T_SEQ - 1);              // multiple of 8
    int rest = id >> 11;                   // kh*64 + d
    ushort outv[8];
    #pragma unroll
    for (int p = 0; p < 8; ++p) outv[p] = QKV[(size_t)(t + p) * QKVN + 3072 + rest];
    int o  = t & 31;
    int q0 = o >> 2;
    int s0 = ((q0 & 3) << 3) + ((q0 >> 2) << 2);
    int s1 = (((q0+1) & 3) << 3) + (((q0+1) >> 2) << 2);
    size_t ob = (size_t)rest * T_SEQ + (t & ~31);
    *(uint2*)(Vt + ob + s0) = *(const uint2*)(outv);
    *(uint2*)(Vt + ob + s1) = *(const uint2*)(outv + 4);
  }
}

// ---------------- flash attention: no in-loop LDS, rotated K prefetch --------------
// 512 blocks = (head, qb). Wave w: stream st = w>>1, q-half qh = w&1 (32 q-rows).
// K/V fragments direct from L2 (frag-interleaved global). Loop is rotated: after
// the QK MFMAs consume kf, the SAME registers are reloaded for tile kt+1, hiding
// L2 latency under softmax+PV. setprio(1) wraps the MFMA clusters (T5).
__global__ __launch_bounds__(256) void attn_kernel(const ushort* __restrict__ Qr,
                                                   const ushort* __restrict__ Kr,
                                                   const ushort* __restrict__ Vt,
                                                   const float* __restrict__ lamp,
                                                   float* __restrict__ Yf,
                                                   float* __restrict__ part) {
  const int bx = blockIdx.x;          // 0..511
  const int h  = bx & 15;
  const int jb = bx >> 4;             // pair (jb, jb+16) sums to 32 tiles
  const int qb = (jb < 16) ? (31 - jb) : (jb - 16);
  const int kh = h >> 1;
  const int tid = threadIdx.x;
  const int lane = tid & 63;
  const int w   = tid >> 6;
  const int st  = w >> 1;             // stream 0/1
  const int qh  = w & 1;              // q-half 0/1
  const int fr  = lane & 15;
  const int fg  = (lane >> 4) * 4;
  const int g8  = (lane >> 4) * 8;

  __shared__ float ob[64 * 64];       // epilogue O2 exchange (16 KB)
  __shared__ float sb[8];

  // Q fragments for this wave's stream, two 16-q chunks (frag-interleaved global)
  bf16x8 qf[2][2];                     // [qs][ks]
  #pragma unroll
  for (int qs = 0; qs < 2; ++qs) {
    const int row = qb * 64 + qh * 32 + qs * 16 + fr;
    const ushort* qp = Qr + ((size_t)(st * NHEAD + h) * T_SEQ + row) * HDIM;
    qf[qs][0] = ldfrag128(qp + g8);
    qf[qs][1] = ldfrag128(qp + 32 + g8);
  }

  float m_[2] = {-__builtin_inff(), -__builtin_inff()};
  float l_[2] = {0.f, 0.f};
  f32x4 o_[2][4];
  #pragma unroll
  for (int qs = 0; qs < 2; ++qs)
    #pragma unroll
    for (int dn = 0; dn < 4; ++dn) o_[qs][dn] = zero4();

  // per-lane fragment base pointers (row picked by fr, 16B chunk by g8)
  const ushort* Kbase = Kr + ((size_t)(st * NKVH + kh) * T_SEQ + fr) * HDIM + g8;
  const ushort* Vbase = Vt + ((size_t)(kh * 64 + fr) * T_SEQ) + g8;

  // K fragments (single buffer, reloaded mid-tile after QK consumes them)
  bf16x8 kf[4][2], vf[4][2];
  #pragma unroll
  for (int n = 0; n < 4; ++n) {
    const ushort* kp = Kbase + (size_t)(n * 16) * HDIM;
    kf[n][0] = ldfrag128(kp);
    kf[n][1] = ldfrag128(kp + 32);
  }

  for (int kt = 0; kt <= qb; ++kt) {
    const int kvb = kt * 64;

    // V fragments for this tile (needed only after softmax -> self-hiding)
    #pragma unroll
    for (int dn = 0; dn < 4; ++dn) {
      const ushort* vp = Vbase + (size_t)(dn * 16) * T_SEQ + kvb;
      vf[dn][0] = ldfrag128(vp);
      vf[dn][1] = ldfrag128(vp + 32);
    }

    // S^T: mfma(K rows, Q cols); one K frag serves both q-chunks
    float sv[2][4][4];
    __builtin_amdgcn_s_setprio(1);
    #pragma unroll
    for (int n = 0; n < 4; ++n) {
      f32x4 a0 = zero4(), a1 = zero4();
      #pragma unroll
      for (int ks = 0; ks < 2; ++ks) {
        a0 = __builtin_amdgcn_mfma_f32_16x16x32_bf16(kf[n][ks], qf[0][ks], a0, 0, 0, 0);
        a1 = __builtin_amdgcn_mfma_f32_16x16x32_bf16(kf[n][ks], qf[1][ks], a1, 0, 0, 0);
      }
      #pragma unroll
      for (int i = 0; i < 4; ++i) { sv[0][n][i] = a0[i]; sv[1][n][i] = a1[i]; }
    }
    __builtin_amdgcn_s_setprio(0);

    // kf is dead now -- reload it for tile kt+1; latency hides under softmax+PV
    if (kt < qb) {
      #pragma unroll
      for (int n = 0; n < 4; ++n) {
        const ushort* kp = Kbase + (size_t)(kvb + 64 + n * 16) * HDIM;
        kf[n][0] = ldfrag128(kp);
        kf[n][1] = ldfrag128(kp + 32);
      }
    }

    if (kt == qb) {                  // causal mask on diagonal tile
      #pragma unroll
      for (int qs = 0; qs < 2; ++qs) {
        const int qloc = qh*32 + qs*16 + fr;
        #pragma unroll
        for (int n = 0; n < 4; ++n)
          #pragma unroll
          for (int i = 0; i < 4; ++i)
            if (n*16 + fg + i > qloc) sv[qs][n][i] = -__builtin_inff();
      }
    }

    bf16x8 pa[2][2];
    #pragma unroll
    for (int qs = 0; qs < 2; ++qs) {
      float rm = -__builtin_inff();
      #pragma unroll
      for (int n = 0; n < 4; ++n)
        #pragma unroll
        for (int i = 0; i < 4; ++i) rm = fmaxf(rm, sv[qs][n][i]);
      rm = fmaxf(rm, __shfl_xor(rm, 16));
      rm = fmaxf(rm, __shfl_xor(rm, 32));
      if (!__all(rm <= m_[qs] + 8.f)) {   // defer-max (exp2 domain, THR=8)
        float mnew = fmaxf(m_[qs], rm);
        float sc = __builtin_amdgcn_exp2f(m_[qs] - mnew);
        m_[qs] = mnew;
        l_[qs] *= sc;
        float scs[4];
        #pragma unroll
        for (int i = 0; i < 4; ++i) scs[i] = __shfl(sc, fg + i);
        #pragma unroll
        for (int dn = 0; dn < 4; ++dn)
          #pragma unroll
          for (int i = 0; i < 4; ++i) o_[qs][dn][i] *= scs[i];
      }
      float rs = 0.f;
      #pragma unroll
      for (int n = 0; n < 4; ++n)
        #pragma unroll
        for (int i = 0; i < 4; ++i) {
          float p = __builtin_amdgcn_exp2f(sv[qs][n][i] - m_[qs]);
          sv[qs][n][i] = p; rs += p;
        }
      rs += __shfl_xor(rs, 16);
      rs += __shfl_xor(rs, 32);
      l_[qs] += rs;
      #pragma unroll
      for (int ks = 0; ks < 2; ++ks)
        #pragma unroll
        for (int n2 = 0; n2 < 2; ++n2)
          #pragma unroll
          for (int i = 0; i < 4; ++i)
            pa[qs][ks][n2*4 + i] = (__bf16)sv[qs][2*ks + n2][i];
    }

    // O += P @ V; one V frag serves both q-chunks
    __builtin_amdgcn_s_setprio(1);
    #pragma unroll
    for (int ks = 0; ks < 2; ++ks)
      #pragma unroll
      for (int dn = 0; dn < 4; ++dn) {
        o_[0][dn] = __builtin_amdgcn_mfma_f32_16x16x32_bf16(pa[0][ks], vf[dn][ks], o_[0][dn], 0, 0, 0);
        o_[1][dn] = __builtin_amdgcn_mfma_f32_16x16x32_bf16(pa[1][ks], vf[dn][ks], o_[1][dn], 0, 0, 0);
      }
    __builtin_amdgcn_s_setprio(0);
  }

  // epilogue: normalize; exchange stream-1 O via LDS; combine + Yf + LN partials
  float iq[2][4];
  #pragma unroll
  for (int qs = 0; qs < 2; ++qs) {
    float inv = __builtin_amdgcn_rcpf(l_[qs]);
    #pragma unroll
    for (int i = 0; i < 4; ++i) iq[qs][i] = __shfl(inv, fg + i);
  }
  __syncthreads();
  if (st == 1) {
    #pragma unroll
    for (int qs = 0; qs < 2; ++qs)
      #pragma unroll
      for (int dn = 0; dn < 4; ++dn)
        #pragma unroll
        for (int i = 0; i < 4; ++i)
          ob[(qh*32 + qs*16 + fg + i)*64 + dn*16 + fr] = o_[qs][dn][i] * iq[qs][i];
  }
  __syncthreads();
  if (st == 0) {
    const float lam = *lamp;
    float s = 0.f, s2 = 0.f;
    #pragma unroll
    for (int qs = 0; qs < 2; ++qs)
      #pragma unroll
      for (int dn = 0; dn < 4; ++dn)
        #pragma unroll
        for (int i = 0; i < 4; ++i) {
          int r64 = qh*32 + qs*16 + fg + i;
          int d   = dn*16 + fr;
          float v = o_[qs][dn][i] * iq[qs][i] - lam * ob[r64*64 + d];
          Yf[(size_t)(qb*64 + r64) * DIM + h*64 + d] = v;
          s += v; s2 += v * v;
        }
    #pragma unroll
    for (int off = 1; off <= 32; off <<= 1) {
      s  += __shfl_xor(s, off);
      s2 += __shfl_xor(s2, off);
    }
    if (lane == 0) { sb[w] = s; sb[4 + w] = s2; }   // w in {0,1}
  }
  __syncthreads();
  if (tid == 0) {
    part[bx]       = sb[0] + sb[1];
    part[512 + bx] = sb[4] + sb[5];
  }
}

// ---------------- finalize per-head stats ----------------
__global__ void stats_final(const float* __restrict__ part, float* __restrict__ stat) {
  int hh = threadIdx.x;
  if (hh < 16) {
    float S = 0.f, S2 = 0.f;
    #pragma unroll
    for (int j = 0; j < 32; ++j) { S += part[j*16 + hh]; S2 += part[512 + j*16 + hh]; }
    const float N = (float)(T_SEQ * HDIM);
    float mean = S / N;
    float var  = S2 / N - mean * mean;
    stat[hh]      = mean;
    stat[16 + hh] = rsqrtf(var + 1e-5f);
  }
}

// Yb written frag-interleaved (gemm2 expects it)
__global__ void norm_cvt(const float* __restrict__ Y, const float* __restrict__ stats,
                         ushort* __restrict__ Yb) {
  int idx = (blockIdx.x * 256 + threadIdx.x) * 4;   // < T*DIM, 4-aligned
  int col = idx & (DIM - 1);
  int h = col >> 6;
  float mean = stats[h], isd = stats[16 + h] * ONE_MINUS_LI;
  float4 v = *(const float4*)(Y + idx);
  ushort4 o4;
  o4.x = f2bf((v.x - mean) * isd);
  o4.y = f2bf((v.y - mean) * isd);
  o4.z = f2bf((v.z - mean) * isd);
  o4.w = f2bf((v.w - mean) * isd);
  int q = (col & 31) >> 2;
  int idxp = (idx & ~31) + ((q & 3) << 3) + ((q >> 2) << 2);
  *(ushort4*)(Yb + idxp) = o4;
}

// ---------------- launch ----------------
extern "C" void kernel_launch(void* const* d_in, const int* in_sizes, int n_in,
                              void* d_out, int out_size, void* d_ws, size_t ws_size,
                              hipStream_t stream) {
  const float* x   = (const float*)d_in[0];
  const float* fc  = (const float*)d_in[1];
  const float* fs  = (const float*)d_in[2];
  const float* wq  = (const float*)d_in[3];
  const float* wk  = (const float*)d_in[4];
  const float* wv  = (const float*)d_in[5];
  const float* wo  = (const float*)d_in[6];
  const float* lq1 = (const float*)d_in[7];
  const float* lk1 = (const float*)d_in[8];
  const float* lq2 = (const float*)d_in[9];
  const float* lk2 = (const float*)d_in[10];
  float* out = (float*)d_out;

  char* ws = (char*)d_ws;
  const size_t OFF_WOB  = 0;                 // 2 MB, live till end
  const size_t OFF_XB   = 2097152;           // 4 MB, dead after gemm1
  const size_t OFF_WB   = 6291456;           // 7 MB, dead after gemm1
  const size_t OFF_QKV  = 13631488;          // 14.68 MB, dead after reorg
  const size_t OFF_QR   = 28311552;          // 8 MB
  const size_t OFF_KR   = 36700160;          // 4 MB
  const size_t OFF_VT   = 40894464;          // 2 MB
  const size_t OFF_Y    = 18874368;          // 8 MB over dead QKV tail
  const size_t OFF_YB   = 42991616;          // 4 MB
  const size_t OFF_ST   = 47185920;          // stats + lam + partials

  ushort* xb   = (ushort*)(ws + OFF_XB);
  ushort* Wb   = (ushort*)(ws + OFF_WB);
  ushort* Wob  = (ushort*)(ws + OFF_WOB);
  ushort* QKVb = (ushort*)(ws + OFF_QKV);
  ushort* Qr   = (ushort*)(ws + OFF_QR);
  ushort* Kr   = (ushort*)(ws + OFF_KR);
  ushort* Vt   = (ushort*)(ws + OFF_VT);
  float*  Yf   = (float*)(ws + OFF_Y);
  ushort* Yb   = (ushort*)(ws + OFF_YB);
  float*  stat = (float*)(ws + OFF_ST);
  float*  lamp = stat + 32;
  float*  part = stat + 64;                  // 1024 floats

  cvt_all<<<6656, 256, 0, stream>>>(x, wq, wk, wv, wo, xb, Wb, Wob);
  lam_kernel<<<1, 64, 0, stream>>>(lq1, lk1, lq2, lk2, lamp);

  gemm_bt<1><<<dim3(QKVN/128, T_SEQ/128), 256, 0, stream>>>(xb, Wb, QKVb, T_SEQ, QKVN, DIM);

  reorg<<<3584, 256, 0, stream>>>(QKVb, Qr, Kr, Vt, fc, fs);

  attn_kernel<<<512, 256, 0, stream>>>(Qr, Kr, Vt, lamp, Yf, part);

  stats_final<<<1, 64, 0, stream>>>(part, stat);
  norm_cvt<<<2048, 256, 0, stream>>>(Yf, stat, Yb);

  gemm_bt<0><<<dim3(DIM/128, T_SEQ/128), 256, 0, stream>>>(Yb, Wob, out, T_SEQ, DIM, DIM);
}